// Round 1
// baseline (1124.067 us; speedup 1.0000x reference)
//
#include <hip/hip_runtime.h>
#include <hip/hip_bf16.h>

// Problem constants (reference: T,H,I,E,K = 4096,1024,2048,32,4)
#define T_TOK 4096
#define H_DIM 1024
#define I_DIM 2048
#define N_EXP 32
#define TOPK  4
#define TKTOT (T_TOK * TOPK)      // 16384 expert-row slots
#define ROWS_MAX 24576            // 4096 shared rows + <=20480 padded expert rows
#define MAX_TILES 192             // 32 shared tiles + <=159 expert tiles
#define BM 128
#define BK 64

typedef _Float16 f16;
typedef __attribute__((ext_vector_type(4))) f16  f16x4;
typedef __attribute__((ext_vector_type(8))) f16  f16x8;
typedef __attribute__((ext_vector_type(4))) float f32x4;

// ---------------------------------------------------------------- prep ----
// convert x fp32 -> f16, prefill row tables (shared rows 0..T-1 => token i,
// weight 1; expert region prefilled token 0 / weight 0), zero counts.
__global__ void prep_kernel(const float* __restrict__ x, f16* __restrict__ xb,
                            int* __restrict__ row_token,
                            float* __restrict__ row_weight,
                            int* __restrict__ counts) {
  int gid = blockIdx.x * blockDim.x + threadIdx.x;   // 0 .. T*H/4-1
  float4 v = *(const float4*)(x + (size_t)gid * 4);
  f16x4 hv = { (f16)v.x, (f16)v.y, (f16)v.z, (f16)v.w };
  *(f16x4*)(xb + (size_t)gid * 4) = hv;
  if (gid < ROWS_MAX) {
    row_token[gid]  = (gid < T_TOK) ? gid : 0;
    row_weight[gid] = (gid < T_TOK) ? 1.f : 0.f;
  }
  if (gid < N_EXP) counts[gid] = 0;
}

// -------------------------------------------------------------- router ----
// fp32 router: logits = x @ rw^T, softmax, top-4 (ties -> lower index),
// renormalize. One wave per token.
__global__ void router_kernel(const float* __restrict__ x,
                              const float* __restrict__ rw,
                              int* __restrict__ expert_sel,
                              float* __restrict__ weight_sel,
                              int* __restrict__ counts) {
  int wid = threadIdx.x >> 6, lane = threadIdx.x & 63;
  int t = blockIdx.x * 4 + wid;
  float xr[16];
#pragma unroll
  for (int j = 0; j < 16; ++j) xr[j] = x[(size_t)t * H_DIM + lane + j * 64];
  float l[32];
#pragma unroll
  for (int e = 0; e < 32; ++e) {
    float p = 0.f;
#pragma unroll
    for (int j = 0; j < 16; ++j) p += xr[j] * rw[(size_t)e * H_DIM + lane + j * 64];
#pragma unroll
    for (int off = 32; off; off >>= 1) p += __shfl_xor(p, off, 64);
    l[e] = p;   // full-wave value; compile-time index (unrolled) -> registers
  }
  if (lane == 0) {
    unsigned used = 0;
    int sel[4]; float lv[4];
#pragma unroll
    for (int k = 0; k < 4; ++k) {
      float bv = -3.4e38f; int bi = 0;
#pragma unroll
      for (int e = 0; e < 32; ++e) {
        bool better = (((used >> e) & 1u) == 0u) && (l[e] > bv);
        bv = better ? l[e] : bv;
        bi = better ? e : bi;
      }
      used |= 1u << bi; sel[k] = bi; lv[k] = bv;
    }
    float m = lv[0];   // top-1 logit == max logit
    float p0 = __expf(lv[0] - m), p1 = __expf(lv[1] - m);
    float p2 = __expf(lv[2] - m), p3 = __expf(lv[3] - m);
    float s = p0 + p1 + p2 + p3;
    float wv[4] = { p0 / s, p1 / s, p2 / s, p3 / s };
#pragma unroll
    for (int k = 0; k < 4; ++k) {
      expert_sel[t * 4 + k] = sel[k];
      weight_sel[t * 4 + k] = wv[k];
      atomicAdd(&counts[sel[k]], 1);
    }
  }
}

// ---------------------------------------------------------------- scan ----
// single-thread: padded per-expert offsets (each expert starts 128-aligned,
// after the fixed shared region rows [0,T)), tile table, cursors.
__global__ void scan_kernel(const int* __restrict__ counts, int* __restrict__ cursor,
                            int* __restrict__ tile_expert, int* __restrict__ tile_row0,
                            int* __restrict__ ntiles) {
  if (threadIdx.x != 0 || blockIdx.x != 0) return;
  int nt = 0;
  for (int i = 0; i < T_TOK / BM; ++i) { tile_expert[nt] = N_EXP; tile_row0[nt] = i * BM; ++nt; }
  int pos = T_TOK;
  for (int e = 0; e < N_EXP; ++e) {
    cursor[e] = pos;
    int c = counts[e];
    int nte = (c + BM - 1) / BM;
    for (int i = 0; i < nte; ++i) { tile_expert[nt] = e; tile_row0[nt] = pos + i * BM; ++nt; }
    pos += nte * BM;
  }
  ntiles[0] = nt;
}

// ------------------------------------------------------------- scatter ----
__global__ void scatter_kernel(const int* __restrict__ expert_sel,
                               const float* __restrict__ weight_sel,
                               int* __restrict__ cursor,
                               int* __restrict__ row_token,
                               float* __restrict__ row_weight) {
  int i = blockIdx.x * blockDim.x + threadIdx.x;
  if (i >= TKTOT) return;
  int e = expert_sel[i];
  int pos = atomicAdd(&cursor[e], 1);
  row_token[pos]  = i >> 2;
  row_weight[pos] = weight_sel[i];
}

// ---------------------------------------------------------------- GEMM1 ---
// h[row, n] = silu(xg[row]·Wg[:,n]) * (xg[row]·Wu[:,n]) for a 128x128 tile.
// A gathered from xb via row_token. Wg/Wu fp32 -> f16 on the fly, stored
// transposed [n][k] in LDS with XOR-swizzled 16B k-groups.
__device__ __forceinline__ int kswz(int row) { return ((row >> 2) & 7) << 3; }

__global__ __launch_bounds__(256) void gemm1_kernel(
    const f16* __restrict__ xb,
    const float* __restrict__ gate_w, const float* __restrict__ up_w,
    const float* __restrict__ sgw, const float* __restrict__ suw,
    const int* __restrict__ row_token,
    const int* __restrict__ tile_expert, const int* __restrict__ tile_row0,
    const int* __restrict__ ntiles, f16* __restrict__ hbuf) {
  int bx = blockIdx.x;
  if (bx >= ntiles[0]) return;
  int e = tile_expert[bx];
  int row0 = tile_row0[bx];
  int n0 = blockIdx.y * 128;
  const float* wg = (e < N_EXP) ? gate_w + (size_t)e * H_DIM * I_DIM : sgw;
  const float* wu = (e < N_EXP) ? up_w   + (size_t)e * H_DIM * I_DIM : suw;

  __shared__ f16 As[BM][BK + 8];
  __shared__ f16 Bg[128][BK + 8];
  __shared__ f16 Bu[128][BK + 8];

  int tid = threadIdx.x;
  int lane = tid & 63, wid = tid >> 6;
  int wm = wid >> 1, wn = wid & 1;
  int lr = lane & 15, lk = (lane >> 4) * 8;

  int atok[4];
#pragma unroll
  for (int it = 0; it < 4; ++it)
    atok[it] = row_token[row0 + ((tid + it * 256) >> 3)];

  f32x4 accg[4][4], accu[4][4];
#pragma unroll
  for (int m = 0; m < 4; ++m)
#pragma unroll
    for (int n = 0; n < 4; ++n) { accg[m][n] = (f32x4)0.f; accu[m][n] = (f32x4)0.f; }

  for (int ks = 0; ks < H_DIM / BK; ++ks) {
    int k0 = ks * BK;
#pragma unroll
    for (int it = 0; it < 4; ++it) {                 // A: 128 rows x 64 f16
      int idx = tid + it * 256;
      int r = idx >> 3, k8 = (idx & 7) * 8;
      *(uint4*)&As[r][k8] =
          *(const uint4*)(xb + (size_t)atok[it] * H_DIM + k0 + k8);
    }
#pragma unroll
    for (int it = 0; it < 8; ++it) {                 // B: transpose 64x128 -> [n][k]
      int idx = (tid + it * 256) * 4;
      int kk = idx >> 7, n = idx & 127;
      float4 g = *(const float4*)(wg + (size_t)(k0 + kk) * I_DIM + n0 + n);
      float4 u = *(const float4*)(wu + (size_t)(k0 + kk) * I_DIM + n0 + n);
      Bg[n + 0][kk ^ kswz(n + 0)] = (f16)g.x;
      Bg[n + 1][kk ^ kswz(n + 1)] = (f16)g.y;
      Bg[n + 2][kk ^ kswz(n + 2)] = (f16)g.z;
      Bg[n + 3][kk ^ kswz(n + 3)] = (f16)g.w;
      Bu[n + 0][kk ^ kswz(n + 0)] = (f16)u.x;
      Bu[n + 1][kk ^ kswz(n + 1)] = (f16)u.y;
      Bu[n + 2][kk ^ kswz(n + 2)] = (f16)u.z;
      Bu[n + 3][kk ^ kswz(n + 3)] = (f16)u.w;
    }
    __syncthreads();
#pragma unroll
    for (int kk = 0; kk < BK; kk += 32) {
      f16x8 a[4], bg[4], bu[4];
#pragma unroll
      for (int m = 0; m < 4; ++m)
        a[m] = *(const f16x8*)&As[wm * 64 + m * 16 + lr][kk + lk];
#pragma unroll
      for (int n = 0; n < 4; ++n) {
        int rowb = wn * 64 + n * 16 + lr;
        bg[n] = *(const f16x8*)&Bg[rowb][(kk + lk) ^ kswz(rowb)];
        bu[n] = *(const f16x8*)&Bu[rowb][(kk + lk) ^ kswz(rowb)];
      }
#pragma unroll
      for (int m = 0; m < 4; ++m)
#pragma unroll
        for (int n = 0; n < 4; ++n) {
          accg[m][n] = __builtin_amdgcn_mfma_f32_16x16x32_f16(a[m], bg[n], accg[m][n], 0, 0, 0);
          accu[m][n] = __builtin_amdgcn_mfma_f32_16x16x32_f16(a[m], bu[n], accu[m][n], 0, 0, 0);
        }
    }
    __syncthreads();
  }
  // epilogue: SwiGLU, store f16 h
#pragma unroll
  for (int m = 0; m < 4; ++m)
#pragma unroll
    for (int j = 0; j < 4; ++j) {
      int r = row0 + wm * 64 + m * 16 + (lane >> 4) * 4 + j;
      f16* hp = hbuf + (size_t)r * I_DIM + n0 + wn * 64 + lr;
#pragma unroll
      for (int n = 0; n < 4; ++n) {
        float g = accg[m][n][j], u = accu[m][n][j];
        float hv = g / (1.f + __expf(-g)) * u;
        hp[n * 16] = (f16)hv;
      }
    }
}

// ---------------------------------------------------------------- GEMM2 ---
// out[token] += weight * (h[row] @ Wd).  Padding rows have weight 0.
__global__ __launch_bounds__(256) void gemm2_kernel(
    const f16* __restrict__ hbuf,
    const float* __restrict__ down_w, const float* __restrict__ sdw,
    const int* __restrict__ row_token, const float* __restrict__ row_weight,
    const int* __restrict__ tile_expert, const int* __restrict__ tile_row0,
    const int* __restrict__ ntiles, float* __restrict__ out) {
  int bx = blockIdx.x;
  if (bx >= ntiles[0]) return;
  int e = tile_expert[bx];
  int row0 = tile_row0[bx];
  int n0 = blockIdx.y * 128;
  const float* wd = (e < N_EXP) ? down_w + (size_t)e * I_DIM * H_DIM : sdw;

  __shared__ f16 As[BM][BK + 8];
  __shared__ f16 Bd[128][BK + 8];

  int tid = threadIdx.x;
  int lane = tid & 63, wid = tid >> 6;
  int wm = wid >> 1, wn = wid & 1;
  int lr = lane & 15, lk = (lane >> 4) * 8;

  f32x4 acc[4][4];
#pragma unroll
  for (int m = 0; m < 4; ++m)
#pragma unroll
    for (int n = 0; n < 4; ++n) acc[m][n] = (f32x4)0.f;

  for (int ks = 0; ks < I_DIM / BK; ++ks) {
    int k0 = ks * BK;
#pragma unroll
    for (int it = 0; it < 4; ++it) {
      int idx = tid + it * 256;
      int r = idx >> 3, k8 = (idx & 7) * 8;
      *(uint4*)&As[r][k8] =
          *(const uint4*)(hbuf + (size_t)(row0 + r) * I_DIM + k0 + k8);
    }
#pragma unroll
    for (int it = 0; it < 8; ++it) {
      int idx = (tid + it * 256) * 4;
      int kk = idx >> 7, n = idx & 127;
      float4 d = *(const float4*)(wd + (size_t)(k0 + kk) * H_DIM + n0 + n);
      Bd[n + 0][kk ^ kswz(n + 0)] = (f16)d.x;
      Bd[n + 1][kk ^ kswz(n + 1)] = (f16)d.y;
      Bd[n + 2][kk ^ kswz(n + 2)] = (f16)d.z;
      Bd[n + 3][kk ^ kswz(n + 3)] = (f16)d.w;
    }
    __syncthreads();
#pragma unroll
    for (int kk = 0; kk < BK; kk += 32) {
      f16x8 a[4], bd[4];
#pragma unroll
      for (int m = 0; m < 4; ++m)
        a[m] = *(const f16x8*)&As[wm * 64 + m * 16 + lr][kk + lk];
#pragma unroll
      for (int n = 0; n < 4; ++n) {
        int rowb = wn * 64 + n * 16 + lr;
        bd[n] = *(const f16x8*)&Bd[rowb][(kk + lk) ^ kswz(rowb)];
      }
#pragma unroll
      for (int m = 0; m < 4; ++m)
#pragma unroll
        for (int n = 0; n < 4; ++n)
          acc[m][n] = __builtin_amdgcn_mfma_f32_16x16x32_f16(a[m], bd[n], acc[m][n], 0, 0, 0);
    }
    __syncthreads();
  }
#pragma unroll
  for (int m = 0; m < 4; ++m)
#pragma unroll
    for (int j = 0; j < 4; ++j) {
      int rr = row0 + wm * 64 + m * 16 + (lane >> 4) * 4 + j;
      int tok = row_token[rr];
      float wgt = row_weight[rr];
      if (wgt != 0.f) {
        float* op = out + (size_t)tok * H_DIM + n0 + wn * 64 + lr;
#pragma unroll
        for (int n = 0; n < 4; ++n) atomicAdd(op + n * 16, wgt * acc[m][n][j]);
      }
    }
}

// ------------------------------------------------------------- launcher ---
extern "C" void kernel_launch(void* const* d_in, const int* in_sizes, int n_in,
                              void* d_out, int out_size, void* d_ws, size_t ws_size,
                              hipStream_t stream) {
  const float* x        = (const float*)d_in[0];
  const float* router_w = (const float*)d_in[1];
  const float* gate_w   = (const float*)d_in[2];
  const float* up_w     = (const float*)d_in[3];
  const float* down_w   = (const float*)d_in[4];
  const float* sgw      = (const float*)d_in[5];
  const float* suw      = (const float*)d_in[6];
  const float* sdw      = (const float*)d_in[7];
  float* out = (float*)d_out;

  char* w = (char*)d_ws;
  f16*   xb         = (f16*)w;   w += (size_t)T_TOK * H_DIM * 2;
  int*   expert_sel = (int*)w;   w += (size_t)TKTOT * 4;
  float* weight_sel = (float*)w; w += (size_t)TKTOT * 4;
  int*   counts     = (int*)w;   w += 256;
  int*   cursor     = (int*)w;   w += 256;
  int*   tile_exp   = (int*)w;   w += MAX_TILES * 4;
  int*   tile_row0  = (int*)w;   w += MAX_TILES * 4;
  int*   ntiles     = (int*)w;   w += 256;
  int*   row_token  = (int*)w;   w += (size_t)ROWS_MAX * 4;
  float* row_weight = (float*)w; w += (size_t)ROWS_MAX * 4;
  f16*   hbuf       = (f16*)w;   w += (size_t)ROWS_MAX * I_DIM * 2;
  if ((size_t)(w - (char*)d_ws) > ws_size) return;  // ws too small: fail loud

  hipMemsetAsync(d_out, 0, (size_t)out_size * sizeof(float), stream);
  prep_kernel<<<(T_TOK * H_DIM / 4) / 256, 256, 0, stream>>>(x, xb, row_token, row_weight, counts);
  router_kernel<<<T_TOK / 4, 256, 0, stream>>>(x, router_w, expert_sel, weight_sel, counts);
  scan_kernel<<<1, 64, 0, stream>>>(counts, cursor, tile_exp, tile_row0, ntiles);
  scatter_kernel<<<TKTOT / 256, 256, 0, stream>>>(expert_sel, weight_sel, cursor, row_token, row_weight);
  gemm1_kernel<<<dim3(MAX_TILES, I_DIM / 128), 256, 0, stream>>>(
      xb, gate_w, up_w, sgw, suw, row_token, tile_exp, tile_row0, ntiles, hbuf);
  gemm2_kernel<<<dim3(MAX_TILES, H_DIM / 128), 256, 0, stream>>>(
      hbuf, down_w, sdw, row_token, row_weight, tile_exp, tile_row0, ntiles, out);
}

// Round 2
// 921.821 us; speedup vs baseline: 1.2194x; 1.2194x over previous
//
#include <hip/hip_runtime.h>
#include <hip/hip_bf16.h>

// Problem constants (reference: T,H,I,E,K = 4096,1024,2048,32,4)
#define T_TOK 4096
#define H_DIM 1024
#define I_DIM 2048
#define N_EXP 32
#define TOPK  4
#define TKTOT (T_TOK * TOPK)      // 16384 expert-row slots
#define ROWS_MAX 24576            // 4096 shared rows + <=20480 padded expert rows
#define MAX_TILES 192             // 32 shared tiles + <=159 expert tiles
#define BM 128
#define BK 64
#define LDB 72                    // BK + 8 f16 pad -> 144 B rows (16B-aligned)

typedef _Float16 f16;
typedef __attribute__((ext_vector_type(4))) f16  f16x4;
typedef __attribute__((ext_vector_type(8))) f16  f16x8;
typedef __attribute__((ext_vector_type(4))) float f32x4;

// ---------------------------------------------------------------- prep ----
__global__ void prep_kernel(const float* __restrict__ x, f16* __restrict__ xb,
                            int* __restrict__ row_token,
                            float* __restrict__ row_weight,
                            int* __restrict__ counts) {
  int gid = blockIdx.x * blockDim.x + threadIdx.x;   // 0 .. T*H/4-1
  float4 v = *(const float4*)(x + (size_t)gid * 4);
  f16x4 hv = { (f16)v.x, (f16)v.y, (f16)v.z, (f16)v.w };
  *(f16x4*)(xb + (size_t)gid * 4) = hv;
  if (gid < ROWS_MAX) {
    row_token[gid]  = (gid < T_TOK) ? gid : 0;
    row_weight[gid] = (gid < T_TOK) ? 1.f : 0.f;
  }
  if (gid < N_EXP) counts[gid] = 0;
}

// -------------------------------------------------------------- router ----
__global__ void router_kernel(const float* __restrict__ x,
                              const float* __restrict__ rw,
                              int* __restrict__ expert_sel,
                              float* __restrict__ weight_sel,
                              int* __restrict__ counts) {
  int wid = threadIdx.x >> 6, lane = threadIdx.x & 63;
  int t = blockIdx.x * 4 + wid;
  float xr[16];
#pragma unroll
  for (int j = 0; j < 16; ++j) xr[j] = x[(size_t)t * H_DIM + lane + j * 64];
  float l[32];
#pragma unroll
  for (int e = 0; e < 32; ++e) {
    float p = 0.f;
#pragma unroll
    for (int j = 0; j < 16; ++j) p += xr[j] * rw[(size_t)e * H_DIM + lane + j * 64];
#pragma unroll
    for (int off = 32; off; off >>= 1) p += __shfl_xor(p, off, 64);
    l[e] = p;
  }
  if (lane == 0) {
    unsigned used = 0;
    int sel[4]; float lv[4];
#pragma unroll
    for (int k = 0; k < 4; ++k) {
      float bv = -3.4e38f; int bi = 0;
#pragma unroll
      for (int e = 0; e < 32; ++e) {
        bool better = (((used >> e) & 1u) == 0u) && (l[e] > bv);
        bv = better ? l[e] : bv;
        bi = better ? e : bi;
      }
      used |= 1u << bi; sel[k] = bi; lv[k] = bv;
    }
    float m = lv[0];
    float p0 = __expf(lv[0] - m), p1 = __expf(lv[1] - m);
    float p2 = __expf(lv[2] - m), p3 = __expf(lv[3] - m);
    float s = p0 + p1 + p2 + p3;
    float wv[4] = { p0 / s, p1 / s, p2 / s, p3 / s };
#pragma unroll
    for (int k = 0; k < 4; ++k) {
      expert_sel[t * 4 + k] = sel[k];
      weight_sel[t * 4 + k] = wv[k];
      atomicAdd(&counts[sel[k]], 1);
    }
  }
}

// ---------------------------------------------------------------- scan ----
__global__ void scan_kernel(const int* __restrict__ counts, int* __restrict__ cursor,
                            int* __restrict__ tile_expert, int* __restrict__ tile_row0,
                            int* __restrict__ ntiles) {
  if (threadIdx.x != 0 || blockIdx.x != 0) return;
  int nt = 0;
  for (int i = 0; i < T_TOK / BM; ++i) { tile_expert[nt] = N_EXP; tile_row0[nt] = i * BM; ++nt; }
  int pos = T_TOK;
  for (int e = 0; e < N_EXP; ++e) {
    cursor[e] = pos;
    int c = counts[e];
    int nte = (c + BM - 1) / BM;
    for (int i = 0; i < nte; ++i) { tile_expert[nt] = e; tile_row0[nt] = pos + i * BM; ++nt; }
    pos += nte * BM;
  }
  ntiles[0] = nt;
}

// ------------------------------------------------------------- scatter ----
__global__ void scatter_kernel(const int* __restrict__ expert_sel,
                               const float* __restrict__ weight_sel,
                               int* __restrict__ cursor,
                               int* __restrict__ row_token,
                               float* __restrict__ row_weight) {
  int i = blockIdx.x * blockDim.x + threadIdx.x;
  if (i >= TKTOT) return;
  int e = expert_sel[i];
  int pos = atomicAdd(&cursor[e], 1);
  row_token[pos]  = i >> 2;
  row_weight[pos] = weight_sel[i];
}

// ------------------------------------------------- B staging (transpose) --
// src points at W[k0+8*kr][n0+4*nq] (fp32, row stride ldn). Loads an 8k x 4n
// block coalesced, converts to f16, writes 4 x f16x8 (16B, aligned) into
// Bs[n][k] transposed layout.
__device__ __forceinline__ void stage_bT(const float* __restrict__ src, size_t ldn,
                                         f16 (*__restrict__ Bs)[LDB], int nq, int kr) {
  float4 g[8];
#pragma unroll
  for (int j = 0; j < 8; ++j) g[j] = *(const float4*)(src + (size_t)j * ldn);
  {
    f16x8 v = { (f16)g[0].x, (f16)g[1].x, (f16)g[2].x, (f16)g[3].x,
                (f16)g[4].x, (f16)g[5].x, (f16)g[6].x, (f16)g[7].x };
    *(f16x8*)&Bs[4 * nq + 0][8 * kr] = v;
  }
  {
    f16x8 v = { (f16)g[0].y, (f16)g[1].y, (f16)g[2].y, (f16)g[3].y,
                (f16)g[4].y, (f16)g[5].y, (f16)g[6].y, (f16)g[7].y };
    *(f16x8*)&Bs[4 * nq + 1][8 * kr] = v;
  }
  {
    f16x8 v = { (f16)g[0].z, (f16)g[1].z, (f16)g[2].z, (f16)g[3].z,
                (f16)g[4].z, (f16)g[5].z, (f16)g[6].z, (f16)g[7].z };
    *(f16x8*)&Bs[4 * nq + 2][8 * kr] = v;
  }
  {
    f16x8 v = { (f16)g[0].w, (f16)g[1].w, (f16)g[2].w, (f16)g[3].w,
                (f16)g[4].w, (f16)g[5].w, (f16)g[6].w, (f16)g[7].w };
    *(f16x8*)&Bs[4 * nq + 3][8 * kr] = v;
  }
}

// ---------------------------------------------------------------- GEMM1 ---
__global__ __launch_bounds__(256) void gemm1_kernel(
    const f16* __restrict__ xb,
    const float* __restrict__ gate_w, const float* __restrict__ up_w,
    const float* __restrict__ sgw, const float* __restrict__ suw,
    const int* __restrict__ row_token,
    const int* __restrict__ tile_expert, const int* __restrict__ tile_row0,
    const int* __restrict__ ntiles, f16* __restrict__ hbuf) {
  // XCD-aware swizzle: logical l enumerates (nblk, tile) with tile fastest;
  // chunks of 384 consecutive l stay on one XCD (grid 192*16 = 8*384).
  int d = blockIdx.y * gridDim.x + blockIdx.x;
  int l = (d & 7) * 384 + (d >> 3);
  int bx = l % MAX_TILES;
  int n0 = (l / MAX_TILES) * 128;
  if (bx >= ntiles[0]) return;
  int e = tile_expert[bx];
  int row0 = tile_row0[bx];
  const float* wg = (e < N_EXP) ? gate_w + (size_t)e * H_DIM * I_DIM : sgw;
  const float* wu = (e < N_EXP) ? up_w   + (size_t)e * H_DIM * I_DIM : suw;

  __shared__ __align__(16) f16 smem[3 * BM * LDB];
  f16 (*As)[LDB] = (f16(*)[LDB])smem;
  f16 (*Bg)[LDB] = (f16(*)[LDB])(smem + BM * LDB);
  f16 (*Bu)[LDB] = (f16(*)[LDB])(smem + 2 * BM * LDB);
  f16 (*Ct)[136] = (f16(*)[136])smem;   // epilogue reuse: 128*136 <= 2*128*72

  int tid = threadIdx.x;
  int lane = tid & 63, wid = tid >> 6;
  int wm = wid >> 1, wn = wid & 1;
  int lr = lane & 15, lk = (lane >> 4) * 8;
  int nq = tid & 31, kr = tid >> 5;

  int atok[4];
#pragma unroll
  for (int it = 0; it < 4; ++it)
    atok[it] = row_token[row0 + ((tid + it * 256) >> 3)];

  f32x4 accg[4][4], accu[4][4];
#pragma unroll
  for (int m = 0; m < 4; ++m)
#pragma unroll
    for (int n = 0; n < 4; ++n) { accg[m][n] = (f32x4)0.f; accu[m][n] = (f32x4)0.f; }

  for (int ks = 0; ks < H_DIM / BK; ++ks) {
    int k0 = ks * BK;
#pragma unroll
    for (int it = 0; it < 4; ++it) {                 // A: 128 rows x 64 f16
      int idx = tid + it * 256;
      int r = idx >> 3, k8 = (idx & 7) * 8;
      *(f16x8*)&As[r][k8] =
          *(const f16x8*)(xb + (size_t)atok[it] * H_DIM + k0 + k8);
    }
    stage_bT(wg + (size_t)(k0 + 8 * kr) * I_DIM + n0 + 4 * nq, I_DIM, Bg, nq, kr);
    stage_bT(wu + (size_t)(k0 + 8 * kr) * I_DIM + n0 + 4 * nq, I_DIM, Bu, nq, kr);
    __syncthreads();
#pragma unroll
    for (int kk = 0; kk < BK; kk += 32) {
      f16x8 a[4], bg[4], bu[4];
#pragma unroll
      for (int m = 0; m < 4; ++m)
        a[m] = *(const f16x8*)&As[wm * 64 + m * 16 + lr][kk + lk];
#pragma unroll
      for (int n = 0; n < 4; ++n) {
        int rowb = wn * 64 + n * 16 + lr;
        bg[n] = *(const f16x8*)&Bg[rowb][kk + lk];
        bu[n] = *(const f16x8*)&Bu[rowb][kk + lk];
      }
#pragma unroll
      for (int m = 0; m < 4; ++m)
#pragma unroll
        for (int n = 0; n < 4; ++n) {
          accg[m][n] = __builtin_amdgcn_mfma_f32_16x16x32_f16(a[m], bg[n], accg[m][n], 0, 0, 0);
          accu[m][n] = __builtin_amdgcn_mfma_f32_16x16x32_f16(a[m], bu[n], accu[m][n], 0, 0, 0);
        }
    }
    __syncthreads();
  }
  // epilogue: SwiGLU -> LDS bounce -> coalesced f16x8 stores
#pragma unroll
  for (int m = 0; m < 4; ++m)
#pragma unroll
    for (int n = 0; n < 4; ++n)
#pragma unroll
      for (int j = 0; j < 4; ++j) {
        float g = accg[m][n][j], u = accu[m][n][j];
        float hv = g / (1.f + __expf(-g)) * u;
        Ct[wm * 64 + m * 16 + (lane >> 4) * 4 + j][wn * 64 + n * 16 + lr] = (f16)hv;
      }
  __syncthreads();
#pragma unroll
  for (int it = 0; it < 8; ++it) {
    int idx = tid + it * 256;
    int r = idx >> 4, g8 = (idx & 15) * 8;
    *(f16x8*)(hbuf + (size_t)(row0 + r) * I_DIM + n0 + g8) = *(const f16x8*)&Ct[r][g8];
  }
}

// ---------------------------------------------------------------- GEMM2 ---
__global__ __launch_bounds__(256) void gemm2_kernel(
    const f16* __restrict__ hbuf,
    const float* __restrict__ down_w, const float* __restrict__ sdw,
    const int* __restrict__ row_token, const float* __restrict__ row_weight,
    const int* __restrict__ tile_expert, const int* __restrict__ tile_row0,
    const int* __restrict__ ntiles, float* __restrict__ out) {
  // grid 192*8 = 8*192: chunks of 192 logical blocks per XCD
  int d = blockIdx.y * gridDim.x + blockIdx.x;
  int l = (d & 7) * 192 + (d >> 3);
  int bx = l % MAX_TILES;
  int n0 = (l / MAX_TILES) * 128;
  if (bx >= ntiles[0]) return;
  int e = tile_expert[bx];
  int row0 = tile_row0[bx];
  const float* wd = (e < N_EXP) ? down_w + (size_t)e * I_DIM * H_DIM : sdw;

  __shared__ __align__(16) f16 smem[2 * BM * LDB];
  f16 (*As)[LDB] = (f16(*)[LDB])smem;
  f16 (*Bd)[LDB] = (f16(*)[LDB])(smem + BM * LDB);

  int tid = threadIdx.x;
  int lane = tid & 63, wid = tid >> 6;
  int wm = wid >> 1, wn = wid & 1;
  int lr = lane & 15, lk = (lane >> 4) * 8;
  int nq = tid & 31, kr = tid >> 5;

  f32x4 acc[4][4];
#pragma unroll
  for (int m = 0; m < 4; ++m)
#pragma unroll
    for (int n = 0; n < 4; ++n) acc[m][n] = (f32x4)0.f;

  for (int ks = 0; ks < I_DIM / BK; ++ks) {
    int k0 = ks * BK;
#pragma unroll
    for (int it = 0; it < 4; ++it) {
      int idx = tid + it * 256;
      int r = idx >> 3, k8 = (idx & 7) * 8;
      *(f16x8*)&As[r][k8] =
          *(const f16x8*)(hbuf + (size_t)(row0 + r) * I_DIM + k0 + k8);
    }
    stage_bT(wd + (size_t)(k0 + 8 * kr) * H_DIM + n0 + 4 * nq, H_DIM, Bd, nq, kr);
    __syncthreads();
#pragma unroll
    for (int kk = 0; kk < BK; kk += 32) {
      f16x8 a[4], bd[4];
#pragma unroll
      for (int m = 0; m < 4; ++m)
        a[m] = *(const f16x8*)&As[wm * 64 + m * 16 + lr][kk + lk];
#pragma unroll
      for (int n = 0; n < 4; ++n)
        bd[n] = *(const f16x8*)&Bd[wn * 64 + n * 16 + lr][kk + lk];
#pragma unroll
      for (int m = 0; m < 4; ++m)
#pragma unroll
        for (int n = 0; n < 4; ++n)
          acc[m][n] = __builtin_amdgcn_mfma_f32_16x16x32_f16(a[m], bd[n], acc[m][n], 0, 0, 0);
    }
    __syncthreads();
  }
#pragma unroll
  for (int m = 0; m < 4; ++m)
#pragma unroll
    for (int j = 0; j < 4; ++j) {
      int rr = row0 + wm * 64 + m * 16 + (lane >> 4) * 4 + j;
      int tok = row_token[rr];
      float wgt = row_weight[rr];
      if (wgt != 0.f) {
        float* op = out + (size_t)tok * H_DIM + n0 + wn * 64 + lr;
#pragma unroll
        for (int n = 0; n < 4; ++n) atomicAdd(op + n * 16, wgt * acc[m][n][j]);
      }
    }
}

// ------------------------------------------------------------- launcher ---
extern "C" void kernel_launch(void* const* d_in, const int* in_sizes, int n_in,
                              void* d_out, int out_size, void* d_ws, size_t ws_size,
                              hipStream_t stream) {
  const float* x        = (const float*)d_in[0];
  const float* router_w = (const float*)d_in[1];
  const float* gate_w   = (const float*)d_in[2];
  const float* up_w     = (const float*)d_in[3];
  const float* down_w   = (const float*)d_in[4];
  const float* sgw      = (const float*)d_in[5];
  const float* suw      = (const float*)d_in[6];
  const float* sdw      = (const float*)d_in[7];
  float* out = (float*)d_out;

  char* w = (char*)d_ws;
  f16*   xb         = (f16*)w;   w += (size_t)T_TOK * H_DIM * 2;
  int*   expert_sel = (int*)w;   w += (size_t)TKTOT * 4;
  float* weight_sel = (float*)w; w += (size_t)TKTOT * 4;
  int*   counts     = (int*)w;   w += 256;
  int*   cursor     = (int*)w;   w += 256;
  int*   tile_exp   = (int*)w;   w += MAX_TILES * 4;
  int*   tile_row0  = (int*)w;   w += MAX_TILES * 4;
  int*   ntiles     = (int*)w;   w += 256;
  int*   row_token  = (int*)w;   w += (size_t)ROWS_MAX * 4;
  float* row_weight = (float*)w; w += (size_t)ROWS_MAX * 4;
  f16*   hbuf       = (f16*)w;   w += (size_t)ROWS_MAX * I_DIM * 2;
  if ((size_t)(w - (char*)d_ws) > ws_size) return;  // ws too small: fail loud

  hipMemsetAsync(d_out, 0, (size_t)out_size * sizeof(float), stream);
  prep_kernel<<<(T_TOK * H_DIM / 4) / 256, 256, 0, stream>>>(x, xb, row_token, row_weight, counts);
  router_kernel<<<T_TOK / 4, 256, 0, stream>>>(x, router_w, expert_sel, weight_sel, counts);
  scan_kernel<<<1, 64, 0, stream>>>(counts, cursor, tile_exp, tile_row0, ntiles);
  scatter_kernel<<<TKTOT / 256, 256, 0, stream>>>(expert_sel, weight_sel, cursor, row_token, row_weight);
  gemm1_kernel<<<dim3(MAX_TILES, I_DIM / 128), 256, 0, stream>>>(
      xb, gate_w, up_w, sgw, suw, row_token, tile_exp, tile_row0, ntiles, hbuf);
  gemm2_kernel<<<dim3(MAX_TILES, H_DIM / 128), 256, 0, stream>>>(
      hbuf, down_w, sdw, row_token, row_weight, tile_exp, tile_row0, ntiles, out);
}

// Round 4
// 877.017 us; speedup vs baseline: 1.2817x; 1.0511x over previous
//
#include <hip/hip_runtime.h>
#include <hip/hip_bf16.h>

// Problem constants (reference: T,H,I,E,K = 4096,1024,2048,32,4)
#define T_TOK 4096
#define H_DIM 1024
#define I_DIM 2048
#define N_EXP 32
#define TOPK  4
#define TKTOT (T_TOK * TOPK)      // 16384 expert-row slots
#define ROWS_MAX 24576            // 4096 shared rows + <=20480 padded expert rows
#define MAX_TILES 192             // 32 shared tiles + <=159 expert tiles
#define BM 128
#define BK 64
#define LDB 72                    // BK + 8 f16 pad -> 144 B rows (16B-aligned)

typedef _Float16 f16;
typedef __attribute__((ext_vector_type(2))) f16  f16x2;
typedef __attribute__((ext_vector_type(4))) f16  f16x4;
typedef __attribute__((ext_vector_type(8))) f16  f16x8;
typedef __attribute__((ext_vector_type(4))) float f32x4;

// ---------------------------------------------------------------- prep ----
__global__ void prep_kernel(const float* __restrict__ x, f16* __restrict__ xb,
                            int* __restrict__ row_token,
                            float* __restrict__ row_weight,
                            int* __restrict__ counts) {
  int gid = blockIdx.x * blockDim.x + threadIdx.x;   // 0 .. T*H/4-1
  float4 v = *(const float4*)(x + (size_t)gid * 4);
  f16x4 hv = { (f16)v.x, (f16)v.y, (f16)v.z, (f16)v.w };
  *(f16x4*)(xb + (size_t)gid * 4) = hv;
  if (gid < ROWS_MAX) {
    row_token[gid]  = (gid < T_TOK) ? gid : 0;
    row_weight[gid] = (gid < T_TOK) ? 1.f : 0.f;
  }
  if (gid < N_EXP) counts[gid] = 0;
}

// -------------------------------------------------------------- router ----
__global__ void router_kernel(const float* __restrict__ x,
                              const float* __restrict__ rw,
                              int* __restrict__ expert_sel,
                              float* __restrict__ weight_sel,
                              int* __restrict__ counts) {
  int wid = threadIdx.x >> 6, lane = threadIdx.x & 63;
  int t = blockIdx.x * 4 + wid;
  float xr[16];
#pragma unroll
  for (int j = 0; j < 16; ++j) xr[j] = x[(size_t)t * H_DIM + lane + j * 64];
  float l[32];
#pragma unroll
  for (int e = 0; e < 32; ++e) {
    float p = 0.f;
#pragma unroll
    for (int j = 0; j < 16; ++j) p += xr[j] * rw[(size_t)e * H_DIM + lane + j * 64];
#pragma unroll
    for (int off = 32; off; off >>= 1) p += __shfl_xor(p, off, 64);
    l[e] = p;
  }
  if (lane == 0) {
    unsigned used = 0;
    int sel[4]; float lv[4];
#pragma unroll
    for (int k = 0; k < 4; ++k) {
      float bv = -3.4e38f; int bi = 0;
#pragma unroll
      for (int e = 0; e < 32; ++e) {
        bool better = (((used >> e) & 1u) == 0u) && (l[e] > bv);
        bv = better ? l[e] : bv;
        bi = better ? e : bi;
      }
      used |= 1u << bi; sel[k] = bi; lv[k] = bv;
    }
    float m = lv[0];
    float p0 = __expf(lv[0] - m), p1 = __expf(lv[1] - m);
    float p2 = __expf(lv[2] - m), p3 = __expf(lv[3] - m);
    float s = p0 + p1 + p2 + p3;
    float wv[4] = { p0 / s, p1 / s, p2 / s, p3 / s };
#pragma unroll
    for (int k = 0; k < 4; ++k) {
      expert_sel[t * 4 + k] = sel[k];
      weight_sel[t * 4 + k] = wv[k];
      atomicAdd(&counts[sel[k]], 1);
    }
  }
}

// ---------------------------------------------------------------- scan ----
__global__ void scan_kernel(const int* __restrict__ counts, int* __restrict__ cursor,
                            int* __restrict__ tile_expert, int* __restrict__ tile_row0,
                            int* __restrict__ ntiles) {
  if (threadIdx.x != 0 || blockIdx.x != 0) return;
  int nt = 0;
  for (int i = 0; i < T_TOK / BM; ++i) { tile_expert[nt] = N_EXP; tile_row0[nt] = i * BM; ++nt; }
  int pos = T_TOK;
  for (int e = 0; e < N_EXP; ++e) {
    cursor[e] = pos;
    int c = counts[e];
    int nte = (c + BM - 1) / BM;
    for (int i = 0; i < nte; ++i) { tile_expert[nt] = e; tile_row0[nt] = pos + i * BM; ++nt; }
    pos += nte * BM;
  }
  ntiles[0] = nt;
}

// ------------------------------------------------------------- scatter ----
__global__ void scatter_kernel(const int* __restrict__ expert_sel,
                               const float* __restrict__ weight_sel,
                               int* __restrict__ cursor,
                               int* __restrict__ row_token,
                               float* __restrict__ row_weight) {
  int i = blockIdx.x * blockDim.x + threadIdx.x;
  if (i >= TKTOT) return;
  int e = expert_sel[i];
  int pos = atomicAdd(&cursor[e], 1);
  row_token[pos]  = i >> 2;
  row_weight[pos] = weight_sel[i];
}

// ------------------------------------------------- B staging (transpose) --
// src points at W[k0+8*kr][n0+4*nq] (fp32, row stride ldn). Loads an 8k x 4n
// block coalesced, packs to f16 via v_cvt_pkrtz (4 instr / f16x8), writes
// 4 x f16x8 (16B, aligned) into Bs[n][k] with a 3-bit XOR swizzle on the 16B
// k-slot keyed on (row>>2)&7 == nq&7 -- spreads the half-wave's writes over
// 8 start banks instead of 2 (row stride 144B == 4 banks; 4*nq rows == 16*nq
// banks == {0,16} was the 16-way conflict).
__device__ __forceinline__ void stage_bT(const float* __restrict__ src, size_t ldn,
                                         f16 (*__restrict__ Bs)[LDB], int nq, int kr) {
  float4 g[8];
#pragma unroll
  for (int j = 0; j < 8; ++j) g[j] = *(const float4*)(src + (size_t)j * ldn);
  const float* ga = (const float*)g;          // ga[j*4 + comp]
  int ks = (8 * kr) ^ ((nq & 7) << 3);        // swizzled 16B slot (f16 units)
#pragma unroll
  for (int i = 0; i < 4; ++i) {
    union { f16x2 p[4]; f16x8 v; } u;
#pragma unroll
    for (int j = 0; j < 4; ++j)
      u.p[j] = __builtin_bit_cast(
          f16x2, __builtin_amdgcn_cvt_pkrtz(ga[(2 * j) * 4 + i],
                                            ga[(2 * j + 1) * 4 + i]));
    *(f16x8*)&Bs[4 * nq + i][ks] = u.v;
  }
}

// mirrored read-side swizzle: kf16 is the 8-aligned f16 offset within the row
__device__ __forceinline__ int bswz(int row, int kf16) {
  return kf16 ^ (((row >> 2) & 7) << 3);
}

// ---------------------------------------------------------------- GEMM1 ---
__global__ __launch_bounds__(256) void gemm1_kernel(
    const f16* __restrict__ xb,
    const float* __restrict__ gate_w, const float* __restrict__ up_w,
    const float* __restrict__ sgw, const float* __restrict__ suw,
    const int* __restrict__ row_token,
    const int* __restrict__ tile_expert, const int* __restrict__ tile_row0,
    const int* __restrict__ ntiles, f16* __restrict__ hbuf) {
  // XCD-aware swizzle: chunks of 384 consecutive logical blocks per XCD
  int d = blockIdx.y * gridDim.x + blockIdx.x;
  int l = (d & 7) * 384 + (d >> 3);
  int bx = l % MAX_TILES;
  int n0 = (l / MAX_TILES) * 128;
  if (bx >= ntiles[0]) return;
  int e = tile_expert[bx];
  int row0 = tile_row0[bx];
  const float* wg = (e < N_EXP) ? gate_w + (size_t)e * H_DIM * I_DIM : sgw;
  const float* wu = (e < N_EXP) ? up_w   + (size_t)e * H_DIM * I_DIM : suw;

  __shared__ __align__(16) f16 smem[3 * BM * LDB];
  f16 (*As)[LDB] = (f16(*)[LDB])smem;
  f16 (*Bg)[LDB] = (f16(*)[LDB])(smem + BM * LDB);
  f16 (*Bu)[LDB] = (f16(*)[LDB])(smem + 2 * BM * LDB);
  f16 (*Ct)[136] = (f16(*)[136])smem;   // epilogue reuse: 128*136 <= 2*128*72

  int tid = threadIdx.x;
  int lane = tid & 63, wid = tid >> 6;
  int wm = wid >> 1, wn = wid & 1;
  int lr = lane & 15, lk = (lane >> 4) * 8;
  int nq = tid & 31, kr = tid >> 5;

  int atok[4];
#pragma unroll
  for (int it = 0; it < 4; ++it)
    atok[it] = row_token[row0 + ((tid + it * 256) >> 3)];

  f32x4 accg[4][4], accu[4][4];
#pragma unroll
  for (int m = 0; m < 4; ++m)
#pragma unroll
    for (int n = 0; n < 4; ++n) { accg[m][n] = (f32x4)0.f; accu[m][n] = (f32x4)0.f; }

  for (int ks = 0; ks < H_DIM / BK; ++ks) {
    int k0 = ks * BK;
#pragma unroll
    for (int it = 0; it < 4; ++it) {                 // A: 128 rows x 64 f16
      int idx = tid + it * 256;
      int r = idx >> 3, k8 = (idx & 7) * 8;
      *(f16x8*)&As[r][k8] =
          *(const f16x8*)(xb + (size_t)atok[it] * H_DIM + k0 + k8);
    }
    stage_bT(wg + (size_t)(k0 + 8 * kr) * I_DIM + n0 + 4 * nq, I_DIM, Bg, nq, kr);
    stage_bT(wu + (size_t)(k0 + 8 * kr) * I_DIM + n0 + 4 * nq, I_DIM, Bu, nq, kr);
    __syncthreads();
#pragma unroll
    for (int kk = 0; kk < BK; kk += 32) {
      f16x8 a[4], bg[4], bu[4];
#pragma unroll
      for (int m = 0; m < 4; ++m)
        a[m] = *(const f16x8*)&As[wm * 64 + m * 16 + lr][kk + lk];
#pragma unroll
      for (int n = 0; n < 4; ++n) {
        int rowb = wn * 64 + n * 16 + lr;
        int ko = bswz(rowb, kk + lk);
        bg[n] = *(const f16x8*)&Bg[rowb][ko];
        bu[n] = *(const f16x8*)&Bu[rowb][ko];
      }
#pragma unroll
      for (int m = 0; m < 4; ++m)
#pragma unroll
        for (int n = 0; n < 4; ++n) {
          accg[m][n] = __builtin_amdgcn_mfma_f32_16x16x32_f16(a[m], bg[n], accg[m][n], 0, 0, 0);
          accu[m][n] = __builtin_amdgcn_mfma_f32_16x16x32_f16(a[m], bu[n], accu[m][n], 0, 0, 0);
        }
    }
    __syncthreads();
  }
  // epilogue: SwiGLU -> LDS bounce -> coalesced f16x8 stores
#pragma unroll
  for (int m = 0; m < 4; ++m)
#pragma unroll
    for (int n = 0; n < 4; ++n)
#pragma unroll
      for (int j = 0; j < 4; ++j) {
        float g = accg[m][n][j], u = accu[m][n][j];
        float hv = g / (1.f + __expf(-g)) * u;
        Ct[wm * 64 + m * 16 + (lane >> 4) * 4 + j][wn * 64 + n * 16 + lr] = (f16)hv;
      }
  __syncthreads();
#pragma unroll
  for (int it = 0; it < 8; ++it) {
    int idx = tid + it * 256;
    int r = idx >> 4, g8 = (idx & 15) * 8;
    *(f16x8*)(hbuf + (size_t)(row0 + r) * I_DIM + n0 + g8) = *(const f16x8*)&Ct[r][g8];
  }
}

// ---------------------------------------------------------------- GEMM2 ---
__global__ __launch_bounds__(256) void gemm2_kernel(
    const f16* __restrict__ hbuf,
    const float* __restrict__ down_w, const float* __restrict__ sdw,
    const int* __restrict__ row_token, const float* __restrict__ row_weight,
    const int* __restrict__ tile_expert, const int* __restrict__ tile_row0,
    const int* __restrict__ ntiles, float* __restrict__ out) {
  // grid 192*8 = 8*192: chunks of 192 logical blocks per XCD
  int d = blockIdx.y * gridDim.x + blockIdx.x;
  int l = (d & 7) * 192 + (d >> 3);
  int bx = l % MAX_TILES;
  int n0 = (l / MAX_TILES) * 128;
  if (bx >= ntiles[0]) return;
  int e = tile_expert[bx];
  int row0 = tile_row0[bx];
  const float* wd = (e < N_EXP) ? down_w + (size_t)e * I_DIM * H_DIM : sdw;

  __shared__ __align__(16) f16 smem[2 * BM * LDB];
  f16 (*As)[LDB] = (f16(*)[LDB])smem;
  f16 (*Bd)[LDB] = (f16(*)[LDB])(smem + BM * LDB);

  int tid = threadIdx.x;
  int lane = tid & 63, wid = tid >> 6;
  int wm = wid >> 1, wn = wid & 1;
  int lr = lane & 15, lk = (lane >> 4) * 8;
  int nq = tid & 31, kr = tid >> 5;

  f32x4 acc[4][4];
#pragma unroll
  for (int m = 0; m < 4; ++m)
#pragma unroll
    for (int n = 0; n < 4; ++n) acc[m][n] = (f32x4)0.f;

  for (int ks = 0; ks < I_DIM / BK; ++ks) {
    int k0 = ks * BK;
#pragma unroll
    for (int it = 0; it < 4; ++it) {
      int idx = tid + it * 256;
      int r = idx >> 3, k8 = (idx & 7) * 8;
      *(f16x8*)&As[r][k8] =
          *(const f16x8*)(hbuf + (size_t)(row0 + r) * I_DIM + k0 + k8);
    }
    stage_bT(wd + (size_t)(k0 + 8 * kr) * H_DIM + n0 + 4 * nq, H_DIM, Bd, nq, kr);
    __syncthreads();
#pragma unroll
    for (int kk = 0; kk < BK; kk += 32) {
      f16x8 a[4], bd[4];
#pragma unroll
      for (int m = 0; m < 4; ++m)
        a[m] = *(const f16x8*)&As[wm * 64 + m * 16 + lr][kk + lk];
#pragma unroll
      for (int n = 0; n < 4; ++n) {
        int rowb = wn * 64 + n * 16 + lr;
        bd[n] = *(const f16x8*)&Bd[rowb][bswz(rowb, kk + lk)];
      }
#pragma unroll
      for (int m = 0; m < 4; ++m)
#pragma unroll
        for (int n = 0; n < 4; ++n)
          acc[m][n] = __builtin_amdgcn_mfma_f32_16x16x32_f16(a[m], bd[n], acc[m][n], 0, 0, 0);
    }
    __syncthreads();
  }
#pragma unroll
  for (int m = 0; m < 4; ++m)
#pragma unroll
    for (int j = 0; j < 4; ++j) {
      int rr = row0 + wm * 64 + m * 16 + (lane >> 4) * 4 + j;
      int tok = row_token[rr];
      float wgt = row_weight[rr];
      if (wgt != 0.f) {
        float* op = out + (size_t)tok * H_DIM + n0 + wn * 64 + lr;
#pragma unroll
        for (int n = 0; n < 4; ++n) atomicAdd(op + n * 16, wgt * acc[m][n][j]);
      }
    }
}

// ------------------------------------------------------------- launcher ---
extern "C" void kernel_launch(void* const* d_in, const int* in_sizes, int n_in,
                              void* d_out, int out_size, void* d_ws, size_t ws_size,
                              hipStream_t stream) {
  const float* x        = (const float*)d_in[0];
  const float* router_w = (const float*)d_in[1];
  const float* gate_w   = (const float*)d_in[2];
  const float* up_w     = (const float*)d_in[3];
  const float* down_w   = (const float*)d_in[4];
  const float* sgw      = (const float*)d_in[5];
  const float* suw      = (const float*)d_in[6];
  const float* sdw      = (const float*)d_in[7];
  float* out = (float*)d_out;

  char* w = (char*)d_ws;
  f16*   xb         = (f16*)w;   w += (size_t)T_TOK * H_DIM * 2;
  int*   expert_sel = (int*)w;   w += (size_t)TKTOT * 4;
  float* weight_sel = (float*)w; w += (size_t)TKTOT * 4;
  int*   counts     = (int*)w;   w += 256;
  int*   cursor     = (int*)w;   w += 256;
  int*   tile_exp   = (int*)w;   w += MAX_TILES * 4;
  int*   tile_row0  = (int*)w;   w += MAX_TILES * 4;
  int*   ntiles     = (int*)w;   w += 256;
  int*   row_token  = (int*)w;   w += (size_t)ROWS_MAX * 4;
  float* row_weight = (float*)w; w += (size_t)ROWS_MAX * 4;
  f16*   hbuf       = (f16*)w;   w += (size_t)ROWS_MAX * I_DIM * 2;
  if ((size_t)(w - (char*)d_ws) > ws_size) return;  // ws too small: fail loud

  (void)hipMemsetAsync(d_out, 0, (size_t)out_size * sizeof(float), stream);
  prep_kernel<<<(T_TOK * H_DIM / 4) / 256, 256, 0, stream>>>(x, xb, row_token, row_weight, counts);
  router_kernel<<<T_TOK / 4, 256, 0, stream>>>(x, router_w, expert_sel, weight_sel, counts);
  scan_kernel<<<1, 64, 0, stream>>>(counts, cursor, tile_exp, tile_row0, ntiles);
  scatter_kernel<<<TKTOT / 256, 256, 0, stream>>>(expert_sel, weight_sel, cursor, row_token, row_weight);
  gemm1_kernel<<<dim3(MAX_TILES, I_DIM / 128), 256, 0, stream>>>(
      xb, gate_w, up_w, sgw, suw, row_token, tile_exp, tile_row0, ntiles, hbuf);
  gemm2_kernel<<<dim3(MAX_TILES, H_DIM / 128), 256, 0, stream>>>(
      hbuf, down_w, sdw, row_token, row_weight, tile_exp, tile_row0, ntiles, out);
}

// Round 5
// 758.434 us; speedup vs baseline: 1.4821x; 1.1564x over previous
//
#include <hip/hip_runtime.h>
#include <hip/hip_bf16.h>

// Problem constants (reference: T,H,I,E,K = 4096,1024,2048,32,4)
#define T_TOK 4096
#define H_DIM 1024
#define I_DIM 2048
#define N_EXP 32
#define TOPK  4
#define TKTOT (T_TOK * TOPK)      // 16384 expert-row slots
#define ROWS_MAX 24576            // 4096 shared rows + <=20480 padded expert rows
#define MAX_TILES 192             // 32 shared tiles + <=159 expert tiles
#define BM 128
#define BK 64
#define LDB 72                    // BK + 8 f16 pad -> 144 B rows (16B-aligned)

typedef _Float16 f16;
typedef __attribute__((ext_vector_type(2))) f16  f16x2;
typedef __attribute__((ext_vector_type(4))) f16  f16x4;
typedef __attribute__((ext_vector_type(8))) f16  f16x8;
typedef __attribute__((ext_vector_type(4))) float f32x4;

// ---------------------------------------------------------------- prep ----
__global__ void prep_kernel(const float* __restrict__ x, f16* __restrict__ xb,
                            int* __restrict__ row_token,
                            float* __restrict__ row_weight,
                            int* __restrict__ counts) {
  int gid = blockIdx.x * blockDim.x + threadIdx.x;   // 0 .. T*H/4-1
  float4 v = *(const float4*)(x + (size_t)gid * 4);
  f16x4 hv = { (f16)v.x, (f16)v.y, (f16)v.z, (f16)v.w };
  *(f16x4*)(xb + (size_t)gid * 4) = hv;
  if (gid < ROWS_MAX) {
    row_token[gid]  = (gid < T_TOK) ? gid : 0;
    row_weight[gid] = (gid < T_TOK) ? 1.f : 0.f;
  }
  if (gid < N_EXP) counts[gid] = 0;
}

// -------------------------------------------------------------- router ----
__global__ void router_kernel(const float* __restrict__ x,
                              const float* __restrict__ rw,
                              int* __restrict__ expert_sel,
                              float* __restrict__ weight_sel,
                              int* __restrict__ counts) {
  int wid = threadIdx.x >> 6, lane = threadIdx.x & 63;
  int t = blockIdx.x * 4 + wid;
  float xr[16];
#pragma unroll
  for (int j = 0; j < 16; ++j) xr[j] = x[(size_t)t * H_DIM + lane + j * 64];
  float l[32];
#pragma unroll
  for (int e = 0; e < 32; ++e) {
    float p = 0.f;
#pragma unroll
    for (int j = 0; j < 16; ++j) p += xr[j] * rw[(size_t)e * H_DIM + lane + j * 64];
#pragma unroll
    for (int off = 32; off; off >>= 1) p += __shfl_xor(p, off, 64);
    l[e] = p;
  }
  if (lane == 0) {
    unsigned used = 0;
    int sel[4]; float lv[4];
#pragma unroll
    for (int k = 0; k < 4; ++k) {
      float bv = -3.4e38f; int bi = 0;
#pragma unroll
      for (int e = 0; e < 32; ++e) {
        bool better = (((used >> e) & 1u) == 0u) && (l[e] > bv);
        bv = better ? l[e] : bv;
        bi = better ? e : bi;
      }
      used |= 1u << bi; sel[k] = bi; lv[k] = bv;
    }
    float m = lv[0];
    float p0 = __expf(lv[0] - m), p1 = __expf(lv[1] - m);
    float p2 = __expf(lv[2] - m), p3 = __expf(lv[3] - m);
    float s = p0 + p1 + p2 + p3;
    float wv[4] = { p0 / s, p1 / s, p2 / s, p3 / s };
#pragma unroll
    for (int k = 0; k < 4; ++k) {
      expert_sel[t * 4 + k] = sel[k];
      weight_sel[t * 4 + k] = wv[k];
      atomicAdd(&counts[sel[k]], 1);
    }
  }
}

// ---------------------------------------------------------------- scan ----
__global__ void scan_kernel(const int* __restrict__ counts, int* __restrict__ cursor,
                            int* __restrict__ tile_expert, int* __restrict__ tile_row0,
                            int* __restrict__ ntiles) {
  if (threadIdx.x != 0 || blockIdx.x != 0) return;
  int nt = 0;
  for (int i = 0; i < T_TOK / BM; ++i) { tile_expert[nt] = N_EXP; tile_row0[nt] = i * BM; ++nt; }
  int pos = T_TOK;
  for (int e = 0; e < N_EXP; ++e) {
    cursor[e] = pos;
    int c = counts[e];
    int nte = (c + BM - 1) / BM;
    for (int i = 0; i < nte; ++i) { tile_expert[nt] = e; tile_row0[nt] = pos + i * BM; ++nt; }
    pos += nte * BM;
  }
  ntiles[0] = nt;
}

// ------------------------------------------------------------- scatter ----
__global__ void scatter_kernel(const int* __restrict__ expert_sel,
                               const float* __restrict__ weight_sel,
                               int* __restrict__ cursor,
                               int* __restrict__ row_token,
                               float* __restrict__ row_weight) {
  int i = blockIdx.x * blockDim.x + threadIdx.x;
  if (i >= TKTOT) return;
  int e = expert_sel[i];
  int pos = atomicAdd(&cursor[e], 1);
  row_token[pos]  = i >> 2;
  row_weight[pos] = weight_sel[i];
}

// --------------------------------------------- B staging, split in halves --
// fetch: 8 coalesced float4 rows (held in regs across the compute phase);
// write: pack to f16 via v_cvt_pkrtz, 4 x 16B LDS writes, 3-bit XOR swizzle
// on the 16B k-slot keyed on nq&7 (spreads write start-banks 2 -> 8+).
struct B8 { float4 g[8]; };

__device__ __forceinline__ B8 fetch_bT(const float* __restrict__ src, size_t ldn) {
  B8 r;
#pragma unroll
  for (int j = 0; j < 8; ++j) r.g[j] = *(const float4*)(src + (size_t)j * ldn);
  return r;
}

__device__ __forceinline__ void write_bT(const B8& b,
                                         f16 (*__restrict__ Bs)[LDB], int nq, int kr) {
  const float* ga = (const float*)b.g;        // ga[j*4 + comp]
  int ks = (8 * kr) ^ ((nq & 7) << 3);        // swizzled 16B slot (f16 units)
#pragma unroll
  for (int i = 0; i < 4; ++i) {
    union { f16x2 p[4]; f16x8 v; } u;
#pragma unroll
    for (int j = 0; j < 4; ++j)
      u.p[j] = __builtin_bit_cast(
          f16x2, __builtin_amdgcn_cvt_pkrtz(ga[(2 * j) * 4 + i],
                                            ga[(2 * j + 1) * 4 + i]));
    *(f16x8*)&Bs[4 * nq + i][ks] = u.v;
  }
}

// mirrored read-side swizzle: kf16 is the 8-aligned f16 offset within the row
__device__ __forceinline__ int bswz(int row, int kf16) {
  return kf16 ^ (((row >> 2) & 7) << 3);
}

// ---------------------------------------------------------------- GEMM1 ---
__global__ __launch_bounds__(256, 2) void gemm1_kernel(
    const f16* __restrict__ xb,
    const float* __restrict__ gate_w, const float* __restrict__ up_w,
    const float* __restrict__ sgw, const float* __restrict__ suw,
    const int* __restrict__ row_token,
    const int* __restrict__ tile_expert, const int* __restrict__ tile_row0,
    const int* __restrict__ ntiles, f16* __restrict__ hbuf) {
  // XCD-aware swizzle: chunks of 384 consecutive logical blocks per XCD
  int d = blockIdx.y * gridDim.x + blockIdx.x;
  int l = (d & 7) * 384 + (d >> 3);
  int bx = l % MAX_TILES;
  int n0 = (l / MAX_TILES) * 128;
  if (bx >= ntiles[0]) return;
  int e = tile_expert[bx];
  int row0 = tile_row0[bx];
  const float* wg = (e < N_EXP) ? gate_w + (size_t)e * H_DIM * I_DIM : sgw;
  const float* wu = (e < N_EXP) ? up_w   + (size_t)e * H_DIM * I_DIM : suw;

  __shared__ __align__(16) f16 smem[3 * BM * LDB];
  f16 (*As)[LDB] = (f16(*)[LDB])smem;
  f16 (*Bg)[LDB] = (f16(*)[LDB])(smem + BM * LDB);
  f16 (*Bu)[LDB] = (f16(*)[LDB])(smem + 2 * BM * LDB);
  f16 (*Ct)[136] = (f16(*)[136])smem;   // epilogue reuse: 128*136 <= 2*128*72

  int tid = threadIdx.x;
  int lane = tid & 63, wid = tid >> 6;
  int wm = wid >> 1, wn = wid & 1;
  int lr = lane & 15, lk = (lane >> 4) * 8;
  int nq = tid & 31, kr = tid >> 5;

  int atok[4];
#pragma unroll
  for (int it = 0; it < 4; ++it)
    atok[it] = row_token[row0 + ((tid + it * 256) >> 3)];

  const float* wgp = wg + (size_t)(8 * kr) * I_DIM + n0 + 4 * nq;
  const float* wup = wu + (size_t)(8 * kr) * I_DIM + n0 + 4 * nq;

  f32x4 accg[4][4], accu[4][4];
#pragma unroll
  for (int m = 0; m < 4; ++m)
#pragma unroll
    for (int n = 0; n < 4; ++n) { accg[m][n] = (f32x4)0.f; accu[m][n] = (f32x4)0.f; }

  // prologue: prefetch tile 0 into registers
  f16x8 pa[4];
#pragma unroll
  for (int it = 0; it < 4; ++it) {
    int idx = tid + it * 256;
    pa[it] = *(const f16x8*)(xb + (size_t)atok[it] * H_DIM + (idx & 7) * 8);
  }
  B8 pg = fetch_bT(wgp, I_DIM);
  B8 pu = fetch_bT(wup, I_DIM);

  for (int ks = 0; ks < H_DIM / BK; ++ks) {
    // write phase: registers -> LDS (vmcnt wait for tile ks lands here)
#pragma unroll
    for (int it = 0; it < 4; ++it) {
      int idx = tid + it * 256;
      *(f16x8*)&As[idx >> 3][(idx & 7) * 8] = pa[it];
    }
    write_bT(pg, Bg, nq, kr);
    write_bT(pu, Bu, nq, kr);
    // issue next tile's global loads (latency hides under MFMA below)
    if (ks + 1 < H_DIM / BK) {
      int k0n = (ks + 1) * BK;
#pragma unroll
      for (int it = 0; it < 4; ++it) {
        int idx = tid + it * 256;
        pa[it] = *(const f16x8*)(xb + (size_t)atok[it] * H_DIM + k0n + (idx & 7) * 8);
      }
      pg = fetch_bT(wgp + (size_t)k0n * I_DIM, I_DIM);
      pu = fetch_bT(wup + (size_t)k0n * I_DIM, I_DIM);
    }
    __syncthreads();
#pragma unroll
    for (int kk = 0; kk < BK; kk += 32) {
      f16x8 a[4], bg[4], bu[4];
#pragma unroll
      for (int m = 0; m < 4; ++m)
        a[m] = *(const f16x8*)&As[wm * 64 + m * 16 + lr][kk + lk];
#pragma unroll
      for (int n = 0; n < 4; ++n) {
        int rowb = wn * 64 + n * 16 + lr;
        int ko = bswz(rowb, kk + lk);
        bg[n] = *(const f16x8*)&Bg[rowb][ko];
        bu[n] = *(const f16x8*)&Bu[rowb][ko];
      }
#pragma unroll
      for (int m = 0; m < 4; ++m)
#pragma unroll
        for (int n = 0; n < 4; ++n) {
          accg[m][n] = __builtin_amdgcn_mfma_f32_16x16x32_f16(a[m], bg[n], accg[m][n], 0, 0, 0);
          accu[m][n] = __builtin_amdgcn_mfma_f32_16x16x32_f16(a[m], bu[n], accu[m][n], 0, 0, 0);
        }
    }
    __syncthreads();
  }
  // epilogue: SwiGLU -> LDS bounce -> coalesced f16x8 stores
#pragma unroll
  for (int m = 0; m < 4; ++m)
#pragma unroll
    for (int n = 0; n < 4; ++n)
#pragma unroll
      for (int j = 0; j < 4; ++j) {
        float g = accg[m][n][j], u = accu[m][n][j];
        float hv = g / (1.f + __expf(-g)) * u;
        Ct[wm * 64 + m * 16 + (lane >> 4) * 4 + j][wn * 64 + n * 16 + lr] = (f16)hv;
      }
  __syncthreads();
#pragma unroll
  for (int it = 0; it < 8; ++it) {
    int idx = tid + it * 256;
    int r = idx >> 4, g8 = (idx & 15) * 8;
    *(f16x8*)(hbuf + (size_t)(row0 + r) * I_DIM + n0 + g8) = *(const f16x8*)&Ct[r][g8];
  }
}

// ---------------------------------------------------------------- GEMM2 ---
__global__ __launch_bounds__(256, 2) void gemm2_kernel(
    const f16* __restrict__ hbuf,
    const float* __restrict__ down_w, const float* __restrict__ sdw,
    const int* __restrict__ row_token, const float* __restrict__ row_weight,
    const int* __restrict__ tile_expert, const int* __restrict__ tile_row0,
    const int* __restrict__ ntiles, float* __restrict__ out) {
  // grid 192*8 = 8*192: chunks of 192 logical blocks per XCD
  int d = blockIdx.y * gridDim.x + blockIdx.x;
  int l = (d & 7) * 192 + (d >> 3);
  int bx = l % MAX_TILES;
  int n0 = (l / MAX_TILES) * 128;
  if (bx >= ntiles[0]) return;
  int e = tile_expert[bx];
  int row0 = tile_row0[bx];
  const float* wd = (e < N_EXP) ? down_w + (size_t)e * I_DIM * H_DIM : sdw;

  __shared__ __align__(16) f16 smem[2 * BM * LDB];
  f16 (*As)[LDB] = (f16(*)[LDB])smem;
  f16 (*Bd)[LDB] = (f16(*)[LDB])(smem + BM * LDB);

  int tid = threadIdx.x;
  int lane = tid & 63, wid = tid >> 6;
  int wm = wid >> 1, wn = wid & 1;
  int lr = lane & 15, lk = (lane >> 4) * 8;
  int nq = tid & 31, kr = tid >> 5;

  const float* wdp = wd + (size_t)(8 * kr) * H_DIM + n0 + 4 * nq;

  f32x4 acc[4][4];
#pragma unroll
  for (int m = 0; m < 4; ++m)
#pragma unroll
    for (int n = 0; n < 4; ++n) acc[m][n] = (f32x4)0.f;

  // prologue: prefetch tile 0
  f16x8 pa[4];
#pragma unroll
  for (int it = 0; it < 4; ++it) {
    int idx = tid + it * 256;
    pa[it] = *(const f16x8*)(hbuf + (size_t)(row0 + (idx >> 3)) * I_DIM + (idx & 7) * 8);
  }
  B8 pd = fetch_bT(wdp, H_DIM);

  for (int ks = 0; ks < I_DIM / BK; ++ks) {
#pragma unroll
    for (int it = 0; it < 4; ++it) {
      int idx = tid + it * 256;
      *(f16x8*)&As[idx >> 3][(idx & 7) * 8] = pa[it];
    }
    write_bT(pd, Bd, nq, kr);
    if (ks + 1 < I_DIM / BK) {
      int k0n = (ks + 1) * BK;
#pragma unroll
      for (int it = 0; it < 4; ++it) {
        int idx = tid + it * 256;
        pa[it] = *(const f16x8*)(hbuf + (size_t)(row0 + (idx >> 3)) * I_DIM + k0n + (idx & 7) * 8);
      }
      pd = fetch_bT(wdp + (size_t)k0n * H_DIM, H_DIM);
    }
    __syncthreads();
#pragma unroll
    for (int kk = 0; kk < BK; kk += 32) {
      f16x8 a[4], bd[4];
#pragma unroll
      for (int m = 0; m < 4; ++m)
        a[m] = *(const f16x8*)&As[wm * 64 + m * 16 + lr][kk + lk];
#pragma unroll
      for (int n = 0; n < 4; ++n) {
        int rowb = wn * 64 + n * 16 + lr;
        bd[n] = *(const f16x8*)&Bd[rowb][bswz(rowb, kk + lk)];
      }
#pragma unroll
      for (int m = 0; m < 4; ++m)
#pragma unroll
        for (int n = 0; n < 4; ++n)
          acc[m][n] = __builtin_amdgcn_mfma_f32_16x16x32_f16(a[m], bd[n], acc[m][n], 0, 0, 0);
    }
    __syncthreads();
  }
#pragma unroll
  for (int m = 0; m < 4; ++m)
#pragma unroll
    for (int j = 0; j < 4; ++j) {
      int rr = row0 + wm * 64 + m * 16 + (lane >> 4) * 4 + j;
      int tok = row_token[rr];
      float wgt = row_weight[rr];
      if (wgt != 0.f) {
        float* op = out + (size_t)tok * H_DIM + n0 + wn * 64 + lr;
#pragma unroll
        for (int n = 0; n < 4; ++n) atomicAdd(op + n * 16, wgt * acc[m][n][j]);
      }
    }
}

// ------------------------------------------------------------- launcher ---
extern "C" void kernel_launch(void* const* d_in, const int* in_sizes, int n_in,
                              void* d_out, int out_size, void* d_ws, size_t ws_size,
                              hipStream_t stream) {
  const float* x        = (const float*)d_in[0];
  const float* router_w = (const float*)d_in[1];
  const float* gate_w   = (const float*)d_in[2];
  const float* up_w     = (const float*)d_in[3];
  const float* down_w   = (const float*)d_in[4];
  const float* sgw      = (const float*)d_in[5];
  const float* suw      = (const float*)d_in[6];
  const float* sdw      = (const float*)d_in[7];
  float* out = (float*)d_out;

  char* w = (char*)d_ws;
  f16*   xb         = (f16*)w;   w += (size_t)T_TOK * H_DIM * 2;
  int*   expert_sel = (int*)w;   w += (size_t)TKTOT * 4;
  float* weight_sel = (float*)w; w += (size_t)TKTOT * 4;
  int*   counts     = (int*)w;   w += 256;
  int*   cursor     = (int*)w;   w += 256;
  int*   tile_exp   = (int*)w;   w += MAX_TILES * 4;
  int*   tile_row0  = (int*)w;   w += MAX_TILES * 4;
  int*   ntiles     = (int*)w;   w += 256;
  int*   row_token  = (int*)w;   w += (size_t)ROWS_MAX * 4;
  float* row_weight = (float*)w; w += (size_t)ROWS_MAX * 4;
  f16*   hbuf       = (f16*)w;   w += (size_t)ROWS_MAX * I_DIM * 2;
  if ((size_t)(w - (char*)d_ws) > ws_size) return;  // ws too small: fail loud

  (void)hipMemsetAsync(d_out, 0, (size_t)out_size * sizeof(float), stream);
  prep_kernel<<<(T_TOK * H_DIM / 4) / 256, 256, 0, stream>>>(x, xb, row_token, row_weight, counts);
  router_kernel<<<T_TOK / 4, 256, 0, stream>>>(x, router_w, expert_sel, weight_sel, counts);
  scan_kernel<<<1, 64, 0, stream>>>(counts, cursor, tile_exp, tile_row0, ntiles);
  scatter_kernel<<<TKTOT / 256, 256, 0, stream>>>(expert_sel, weight_sel, cursor, row_token, row_weight);
  gemm1_kernel<<<dim3(MAX_TILES, I_DIM / 128), 256, 0, stream>>>(
      xb, gate_w, up_w, sgw, suw, row_token, tile_exp, tile_row0, ntiles, hbuf);
  gemm2_kernel<<<dim3(MAX_TILES, H_DIM / 128), 256, 0, stream>>>(
      hbuf, down_w, sdw, row_token, row_weight, tile_exp, tile_row0, ntiles, out);
}

// Round 6
// 669.507 us; speedup vs baseline: 1.6789x; 1.1328x over previous
//
#include <hip/hip_runtime.h>
#include <hip/hip_bf16.h>

// Problem constants (reference: T,H,I,E,K = 4096,1024,2048,32,4)
#define T_TOK 4096
#define H_DIM 1024
#define I_DIM 2048
#define N_EXP 32
#define TOPK  4
#define TKTOT (T_TOK * TOPK)      // 16384 expert-row slots
#define ROWS_MAX 24576            // 4096 shared rows + <=20480 padded expert rows
#define MAX_TILES 192             // 32 shared tiles + <=159 expert tiles
#define BM 128
#define BK 64
#define LDB 72                    // BK + 8 f16 pad -> 144 B rows (16B-aligned)

typedef _Float16 f16;
typedef __attribute__((ext_vector_type(2))) f16  f16x2;
typedef __attribute__((ext_vector_type(4))) f16  f16x4;
typedef __attribute__((ext_vector_type(8))) f16  f16x8;
typedef __attribute__((ext_vector_type(4))) float f32x4;

// ---------------------------------------------------------------- prep ----
__global__ void prep_kernel(const float* __restrict__ x, f16* __restrict__ xb,
                            int* __restrict__ row_token,
                            float* __restrict__ row_weight,
                            int* __restrict__ counts) {
  int gid = blockIdx.x * blockDim.x + threadIdx.x;   // 0 .. T*H/4-1
  float4 v = *(const float4*)(x + (size_t)gid * 4);
  f16x4 hv = { (f16)v.x, (f16)v.y, (f16)v.z, (f16)v.w };
  *(f16x4*)(xb + (size_t)gid * 4) = hv;
  if (gid < ROWS_MAX) {
    row_token[gid]  = (gid < T_TOK) ? gid : 0;
    row_weight[gid] = (gid < T_TOK) ? 1.f : 0.f;
  }
  if (gid < N_EXP) counts[gid] = 0;
}

// -------------------------------------------------------------- router ----
__global__ void router_kernel(const float* __restrict__ x,
                              const float* __restrict__ rw,
                              int* __restrict__ expert_sel,
                              float* __restrict__ weight_sel,
                              int* __restrict__ counts) {
  int wid = threadIdx.x >> 6, lane = threadIdx.x & 63;
  int t = blockIdx.x * 4 + wid;
  float xr[16];
#pragma unroll
  for (int j = 0; j < 16; ++j) xr[j] = x[(size_t)t * H_DIM + lane + j * 64];
  float l[32];
#pragma unroll
  for (int e = 0; e < 32; ++e) {
    float p = 0.f;
#pragma unroll
    for (int j = 0; j < 16; ++j) p += xr[j] * rw[(size_t)e * H_DIM + lane + j * 64];
#pragma unroll
    for (int off = 32; off; off >>= 1) p += __shfl_xor(p, off, 64);
    l[e] = p;
  }
  if (lane == 0) {
    unsigned used = 0;
    int sel[4]; float lv[4];
#pragma unroll
    for (int k = 0; k < 4; ++k) {
      float bv = -3.4e38f; int bi = 0;
#pragma unroll
      for (int e = 0; e < 32; ++e) {
        bool better = (((used >> e) & 1u) == 0u) && (l[e] > bv);
        bv = better ? l[e] : bv;
        bi = better ? e : bi;
      }
      used |= 1u << bi; sel[k] = bi; lv[k] = bv;
    }
    float m = lv[0];
    float p0 = __expf(lv[0] - m), p1 = __expf(lv[1] - m);
    float p2 = __expf(lv[2] - m), p3 = __expf(lv[3] - m);
    float s = p0 + p1 + p2 + p3;
    float wv[4] = { p0 / s, p1 / s, p2 / s, p3 / s };
#pragma unroll
    for (int k = 0; k < 4; ++k) {
      expert_sel[t * 4 + k] = sel[k];
      weight_sel[t * 4 + k] = wv[k];
      atomicAdd(&counts[sel[k]], 1);
    }
  }
}

// ---------------------------------------------------------------- scan ----
__global__ void scan_kernel(const int* __restrict__ counts, int* __restrict__ cursor,
                            int* __restrict__ tile_expert, int* __restrict__ tile_row0,
                            int* __restrict__ ntiles) {
  if (threadIdx.x != 0 || blockIdx.x != 0) return;
  int nt = 0;
  for (int i = 0; i < T_TOK / BM; ++i) { tile_expert[nt] = N_EXP; tile_row0[nt] = i * BM; ++nt; }
  int pos = T_TOK;
  for (int e = 0; e < N_EXP; ++e) {
    cursor[e] = pos;
    int c = counts[e];
    int nte = (c + BM - 1) / BM;
    for (int i = 0; i < nte; ++i) { tile_expert[nt] = e; tile_row0[nt] = pos + i * BM; ++nt; }
    pos += nte * BM;
  }
  ntiles[0] = nt;
}

// ------------------------------------------------------------- scatter ----
__global__ void scatter_kernel(const int* __restrict__ expert_sel,
                               const float* __restrict__ weight_sel,
                               int* __restrict__ cursor,
                               int* __restrict__ row_token,
                               float* __restrict__ row_weight) {
  int i = blockIdx.x * blockDim.x + threadIdx.x;
  if (i >= TKTOT) return;
  int e = expert_sel[i];
  int pos = atomicAdd(&cursor[e], 1);
  row_token[pos]  = i >> 2;
  row_weight[pos] = weight_sel[i];
}

// ------------------------- B staging helpers (fetch regs / cvt+write LDS) --
// gemm1 (BN=64): thread covers 2 n x 8 k via float2 rows. 16 VGPR/matrix.
struct Bf2 { float2 g[8]; };
__device__ __forceinline__ Bf2 fetch_b2(const float* __restrict__ src, size_t ldn) {
  Bf2 r;
#pragma unroll
  for (int j = 0; j < 8; ++j) r.g[j] = *(const float2*)(src + (size_t)j * ldn);
  return r;
}
__device__ __forceinline__ void write_b2(const Bf2& b,
                                         f16 (*__restrict__ Bs)[LDB], int nq, int kr) {
  const float* ga = (const float*)b.g;        // ga[j*2 + comp]
  int ks = (8 * kr) ^ ((nq & 7) << 3);        // swizzled 16B slot (f16 units)
#pragma unroll
  for (int i = 0; i < 2; ++i) {
    union { f16x2 p[4]; f16x8 v; } u;
#pragma unroll
    for (int j = 0; j < 4; ++j)
      u.p[j] = __builtin_bit_cast(
          f16x2, __builtin_amdgcn_cvt_pkrtz(ga[(2 * j) * 2 + i],
                                            ga[(2 * j + 1) * 2 + i]));
    *(f16x8*)&Bs[2 * nq + i][ks] = u.v;
  }
}
// read-side mirror for gemm1 layout: write row = 2*nq+i -> key (row>>1)&7
__device__ __forceinline__ int rswz1(int row, int kf16) {
  return kf16 ^ (((row >> 1) & 7) << 3);
}

// gemm2 (BN=128): thread covers 4 n x 8 k via float4 rows. 32 VGPR.
struct Bf4 { float4 g[8]; };
__device__ __forceinline__ Bf4 fetch_b4(const float* __restrict__ src, size_t ldn) {
  Bf4 r;
#pragma unroll
  for (int j = 0; j < 8; ++j) r.g[j] = *(const float4*)(src + (size_t)j * ldn);
  return r;
}
__device__ __forceinline__ void write_b4(const Bf4& b,
                                         f16 (*__restrict__ Bs)[LDB], int nq, int kr) {
  const float* ga = (const float*)b.g;        // ga[j*4 + comp]
  int ks = (8 * kr) ^ ((nq & 7) << 3);
#pragma unroll
  for (int i = 0; i < 4; ++i) {
    union { f16x2 p[4]; f16x8 v; } u;
#pragma unroll
    for (int j = 0; j < 4; ++j)
      u.p[j] = __builtin_bit_cast(
          f16x2, __builtin_amdgcn_cvt_pkrtz(ga[(2 * j) * 4 + i],
                                            ga[(2 * j + 1) * 4 + i]));
    *(f16x8*)&Bs[4 * nq + i][ks] = u.v;
  }
}
// read-side mirror for gemm2 layout: write row = 4*nq+i -> key (row>>2)&7
__device__ __forceinline__ int rswz2(int row, int kf16) {
  return kf16 ^ (((row >> 2) & 7) << 3);
}

// ---------------------------------------------------------------- GEMM1 ---
// BN=64: per block 128 rows x 64 cols of gate AND up. 4 waves (2 wm x 2 wn),
// per wave 64x32 per matrix -> acc 4x2x2x4 = 64 f32/lane. 3 blocks/CU.
__global__ __launch_bounds__(256, 3) void gemm1_kernel(
    const f16* __restrict__ xb,
    const float* __restrict__ gate_w, const float* __restrict__ up_w,
    const float* __restrict__ sgw, const float* __restrict__ suw,
    const int* __restrict__ row_token,
    const int* __restrict__ tile_expert, const int* __restrict__ tile_row0,
    const int* __restrict__ ntiles, f16* __restrict__ hbuf) {
  // XCD-aware swizzle: grid 192*32 = 6144 = 8*768 consecutive per XCD
  int d = blockIdx.y * gridDim.x + blockIdx.x;
  int l = (d & 7) * 768 + (d >> 3);
  int bx = l % MAX_TILES;
  int n0 = (l / MAX_TILES) * 64;
  if (bx >= ntiles[0]) return;
  int e = tile_expert[bx];
  int row0 = tile_row0[bx];
  const float* wg = (e < N_EXP) ? gate_w + (size_t)e * H_DIM * I_DIM : sgw;
  const float* wu = (e < N_EXP) ? up_w   + (size_t)e * H_DIM * I_DIM : suw;

  __shared__ __align__(16) f16 smem[BM * LDB + 2 * 64 * LDB];
  f16 (*As)[LDB] = (f16(*)[LDB])smem;
  f16 (*Bg)[LDB] = (f16(*)[LDB])(smem + BM * LDB);
  f16 (*Bu)[LDB] = (f16(*)[LDB])(smem + BM * LDB + 64 * LDB);
  f16 (*Ct)[LDB] = (f16(*)[LDB])smem;   // epilogue reuse: 128*72 == As region

  int tid = threadIdx.x;
  int lane = tid & 63, wid = tid >> 6;
  int wm = wid >> 1, wn = wid & 1;
  int lr = lane & 15, lk = (lane >> 4) * 8;
  int nq = tid & 31, kr = tid >> 5;

  int atok[4];
#pragma unroll
  for (int it = 0; it < 4; ++it)
    atok[it] = row_token[row0 + ((tid + it * 256) >> 3)];

  const float* wgp = wg + (size_t)(8 * kr) * I_DIM + n0 + 2 * nq;
  const float* wup = wu + (size_t)(8 * kr) * I_DIM + n0 + 2 * nq;

  f32x4 accg[4][2], accu[4][2];
#pragma unroll
  for (int m = 0; m < 4; ++m)
#pragma unroll
    for (int n = 0; n < 2; ++n) { accg[m][n] = (f32x4)0.f; accu[m][n] = (f32x4)0.f; }

  // prologue: prefetch tile 0 into registers
  f16x8 pa[4];
#pragma unroll
  for (int it = 0; it < 4; ++it) {
    int idx = tid + it * 256;
    pa[it] = *(const f16x8*)(xb + (size_t)atok[it] * H_DIM + (idx & 7) * 8);
  }
  Bf2 pg = fetch_b2(wgp, I_DIM);
  Bf2 pu = fetch_b2(wup, I_DIM);

  for (int ks = 0; ks < H_DIM / BK; ++ks) {
    // write phase: registers -> LDS (vmcnt wait for tile ks lands here)
#pragma unroll
    for (int it = 0; it < 4; ++it) {
      int idx = tid + it * 256;
      *(f16x8*)&As[idx >> 3][(idx & 7) * 8] = pa[it];
    }
    write_b2(pg, Bg, nq, kr);
    write_b2(pu, Bu, nq, kr);
    // issue next tile's global loads (latency hides under MFMA below)
    if (ks + 1 < H_DIM / BK) {
      int k0n = (ks + 1) * BK;
#pragma unroll
      for (int it = 0; it < 4; ++it) {
        int idx = tid + it * 256;
        pa[it] = *(const f16x8*)(xb + (size_t)atok[it] * H_DIM + k0n + (idx & 7) * 8);
      }
      pg = fetch_b2(wgp + (size_t)k0n * I_DIM, I_DIM);
      pu = fetch_b2(wup + (size_t)k0n * I_DIM, I_DIM);
    }
    __syncthreads();
#pragma unroll
    for (int kk = 0; kk < BK; kk += 32) {
      f16x8 a[4], bg[2], bu[2];
#pragma unroll
      for (int m = 0; m < 4; ++m)
        a[m] = *(const f16x8*)&As[wm * 64 + m * 16 + lr][kk + lk];
#pragma unroll
      for (int n = 0; n < 2; ++n) {
        int rowb = wn * 32 + n * 16 + lr;
        int ko = rswz1(rowb, kk + lk);
        bg[n] = *(const f16x8*)&Bg[rowb][ko];
        bu[n] = *(const f16x8*)&Bu[rowb][ko];
      }
#pragma unroll
      for (int m = 0; m < 4; ++m)
#pragma unroll
        for (int n = 0; n < 2; ++n) {
          accg[m][n] = __builtin_amdgcn_mfma_f32_16x16x32_f16(a[m], bg[n], accg[m][n], 0, 0, 0);
          accu[m][n] = __builtin_amdgcn_mfma_f32_16x16x32_f16(a[m], bu[n], accu[m][n], 0, 0, 0);
        }
    }
    __syncthreads();
  }
  // epilogue: SwiGLU -> LDS bounce -> coalesced f16x8 stores (64 cols/row)
#pragma unroll
  for (int m = 0; m < 4; ++m)
#pragma unroll
    for (int n = 0; n < 2; ++n)
#pragma unroll
      for (int j = 0; j < 4; ++j) {
        float g = accg[m][n][j], u = accu[m][n][j];
        float hv = g / (1.f + __expf(-g)) * u;
        Ct[wm * 64 + m * 16 + (lane >> 4) * 4 + j][wn * 32 + n * 16 + lr] = (f16)hv;
      }
  __syncthreads();
#pragma unroll
  for (int it = 0; it < 4; ++it) {
    int idx = tid + it * 256;
    int r = idx >> 3, g8 = (idx & 7) * 8;
    *(f16x8*)(hbuf + (size_t)(row0 + r) * I_DIM + n0 + g8) = *(const f16x8*)&Ct[r][g8];
  }
}

// ---------------------------------------------------------------- GEMM2 ---
__global__ __launch_bounds__(256, 3) void gemm2_kernel(
    const f16* __restrict__ hbuf,
    const float* __restrict__ down_w, const float* __restrict__ sdw,
    const int* __restrict__ row_token, const float* __restrict__ row_weight,
    const int* __restrict__ tile_expert, const int* __restrict__ tile_row0,
    const int* __restrict__ ntiles, float* __restrict__ out) {
  // grid 192*8 = 8*192: chunks of 192 logical blocks per XCD
  int d = blockIdx.y * gridDim.x + blockIdx.x;
  int l = (d & 7) * 192 + (d >> 3);
  int bx = l % MAX_TILES;
  int n0 = (l / MAX_TILES) * 128;
  if (bx >= ntiles[0]) return;
  int e = tile_expert[bx];
  int row0 = tile_row0[bx];
  const float* wd = (e < N_EXP) ? down_w + (size_t)e * I_DIM * H_DIM : sdw;

  __shared__ __align__(16) f16 smem[2 * BM * LDB];
  f16 (*As)[LDB] = (f16(*)[LDB])smem;
  f16 (*Bd)[LDB] = (f16(*)[LDB])(smem + BM * LDB);

  int tid = threadIdx.x;
  int lane = tid & 63, wid = tid >> 6;
  int wm = wid >> 1, wn = wid & 1;
  int lr = lane & 15, lk = (lane >> 4) * 8;
  int nq = tid & 31, kr = tid >> 5;

  const float* wdp = wd + (size_t)(8 * kr) * H_DIM + n0 + 4 * nq;

  f32x4 acc[4][4];
#pragma unroll
  for (int m = 0; m < 4; ++m)
#pragma unroll
    for (int n = 0; n < 4; ++n) acc[m][n] = (f32x4)0.f;

  // prologue: prefetch tile 0
  f16x8 pa[4];
#pragma unroll
  for (int it = 0; it < 4; ++it) {
    int idx = tid + it * 256;
    pa[it] = *(const f16x8*)(hbuf + (size_t)(row0 + (idx >> 3)) * I_DIM + (idx & 7) * 8);
  }
  Bf4 pd = fetch_b4(wdp, H_DIM);

  for (int ks = 0; ks < I_DIM / BK; ++ks) {
#pragma unroll
    for (int it = 0; it < 4; ++it) {
      int idx = tid + it * 256;
      *(f16x8*)&As[idx >> 3][(idx & 7) * 8] = pa[it];
    }
    write_b4(pd, Bd, nq, kr);
    if (ks + 1 < I_DIM / BK) {
      int k0n = (ks + 1) * BK;
#pragma unroll
      for (int it = 0; it < 4; ++it) {
        int idx = tid + it * 256;
        pa[it] = *(const f16x8*)(hbuf + (size_t)(row0 + (idx >> 3)) * I_DIM + k0n + (idx & 7) * 8);
      }
      pd = fetch_b4(wdp + (size_t)k0n * H_DIM, H_DIM);
    }
    __syncthreads();
#pragma unroll
    for (int kk = 0; kk < BK; kk += 32) {
      f16x8 a[4], bd[4];
#pragma unroll
      for (int m = 0; m < 4; ++m)
        a[m] = *(const f16x8*)&As[wm * 64 + m * 16 + lr][kk + lk];
#pragma unroll
      for (int n = 0; n < 4; ++n) {
        int rowb = wn * 64 + n * 16 + lr;
        bd[n] = *(const f16x8*)&Bd[rowb][rswz2(rowb, kk + lk)];
      }
#pragma unroll
      for (int m = 0; m < 4; ++m)
#pragma unroll
        for (int n = 0; n < 4; ++n)
          acc[m][n] = __builtin_amdgcn_mfma_f32_16x16x32_f16(a[m], bd[n], acc[m][n], 0, 0, 0);
    }
    __syncthreads();
  }
#pragma unroll
  for (int m = 0; m < 4; ++m)
#pragma unroll
    for (int j = 0; j < 4; ++j) {
      int rr = row0 + wm * 64 + m * 16 + (lane >> 4) * 4 + j;
      int tok = row_token[rr];
      float wgt = row_weight[rr];
      if (wgt != 0.f) {
        float* op = out + (size_t)tok * H_DIM + n0 + wn * 64 + lr;
#pragma unroll
        for (int n = 0; n < 4; ++n) atomicAdd(op + n * 16, wgt * acc[m][n][j]);
      }
    }
}

// ------------------------------------------------------------- launcher ---
extern "C" void kernel_launch(void* const* d_in, const int* in_sizes, int n_in,
                              void* d_out, int out_size, void* d_ws, size_t ws_size,
                              hipStream_t stream) {
  const float* x        = (const float*)d_in[0];
  const float* router_w = (const float*)d_in[1];
  const float* gate_w   = (const float*)d_in[2];
  const float* up_w     = (const float*)d_in[3];
  const float* down_w   = (const float*)d_in[4];
  const float* sgw      = (const float*)d_in[5];
  const float* suw      = (const float*)d_in[6];
  const float* sdw      = (const float*)d_in[7];
  float* out = (float*)d_out;

  char* w = (char*)d_ws;
  f16*   xb         = (f16*)w;   w += (size_t)T_TOK * H_DIM * 2;
  int*   expert_sel = (int*)w;   w += (size_t)TKTOT * 4;
  float* weight_sel = (float*)w; w += (size_t)TKTOT * 4;
  int*   counts     = (int*)w;   w += 256;
  int*   cursor     = (int*)w;   w += 256;
  int*   tile_exp   = (int*)w;   w += MAX_TILES * 4;
  int*   tile_row0  = (int*)w;   w += MAX_TILES * 4;
  int*   ntiles     = (int*)w;   w += 256;
  int*   row_token  = (int*)w;   w += (size_t)ROWS_MAX * 4;
  float* row_weight = (float*)w; w += (size_t)ROWS_MAX * 4;
  f16*   hbuf       = (f16*)w;   w += (size_t)ROWS_MAX * I_DIM * 2;
  if ((size_t)(w - (char*)d_ws) > ws_size) return;  // ws too small: fail loud

  (void)hipMemsetAsync(d_out, 0, (size_t)out_size * sizeof(float), stream);
  prep_kernel<<<(T_TOK * H_DIM / 4) / 256, 256, 0, stream>>>(x, xb, row_token, row_weight, counts);
  router_kernel<<<T_TOK / 4, 256, 0, stream>>>(x, router_w, expert_sel, weight_sel, counts);
  scan_kernel<<<1, 64, 0, stream>>>(counts, cursor, tile_exp, tile_row0, ntiles);
  scatter_kernel<<<TKTOT / 256, 256, 0, stream>>>(expert_sel, weight_sel, cursor, row_token, row_weight);
  gemm1_kernel<<<dim3(MAX_TILES, I_DIM / 64), 256, 0, stream>>>(
      xb, gate_w, up_w, sgw, suw, row_token, tile_exp, tile_row0, ntiles, hbuf);
  gemm2_kernel<<<dim3(MAX_TILES, H_DIM / 128), 256, 0, stream>>>(
      hbuf, down_w, sdw, row_token, row_weight, tile_exp, tile_row0, ntiles, out);
}